// Round 16
// baseline (17.548 us; speedup 1.0000x reference)
//
#include <hip/hip_runtime.h>
#include <math.h>

// Realspace Ewald: pot = 2 * sum_{i<j} q_i q_j erf(d_ij/sqrt(2))/d_ij * NORM/(4pi)
// N=6144. erf via A&S 7.1.23 rational (absmax 0.0 since R6), Estrin, packed
// fp32 2-i-per-lane (R12). R16: WHOLE-TILE REGISTER PRELOAD. Evidence: ~130cyc
// fixed overhead per inner iter (R14 marginal-cost calibration) = exposed LDS
// read latency (~120cyc, m117); compiler won't hoist (VGPR pinned ~28).
// Fix: 16 float4 tile -> named registers before the loop (one lgkm drain per
// 16 pairs2), inner loop 100% LDS-free. VGPR ~90 expected (the tell).

#if __has_builtin(__builtin_amdgcn_rsqf)
#define FRSQ(x) __builtin_amdgcn_rsqf(x)
#else
#define FRSQ(x) rsqrtf(x)
#endif
#if __has_builtin(__builtin_amdgcn_rcpf)
#define FRCP(x) __builtin_amdgcn_rcpf(x)
#else
#define FRCP(x) (1.0f / (x))
#endif

typedef float vf2 __attribute__((ext_vector_type(2)));

__device__ __forceinline__ vf2 vfma(vf2 a, vf2 b, vf2 c) {
  return __builtin_elementwise_fma(a, b, c);
}

// A&S 7.1.23 coefficients pre-multiplied by (1/sqrt(2))^k so poly is in d:
#define B1 0.19685360f
#define B2 0.11519450f
#define B3 0.00034366f
#define B4 0.01952700f

template <bool CHECK>
__device__ __forceinline__ void pair2_body(const float4 v, int jj, int i0,
                                           vf2 xi, vf2 yi, vf2 zi, vf2& acc) {
  vf2 dx = xi - v.x, dy = yi - v.y, dz = zi - v.z;
  vf2 s = vfma(dx, dx, vfma(dy, dy, dz * dz));
  vf2 qk = {v.w, v.w};
  if (CHECK) {
    bool t0 = (jj > i0);
    bool t1 = (jj > i0 + 64);
    s.x = t0 ? s.x : 1.0f;
    s.y = t1 ? s.y : 1.0f;
    qk.x = t0 ? qk.x : 0.0f;
    qk.y = t1 ? qk.y : 0.0f;
  }
  vf2 ri;
  ri.x = FRSQ(s.x);
  ri.y = FRSQ(s.y);
  // Estrin: poly = (1 + B2 s + B4 s^2) + d*(B1 + B3 s); E,O overlap rsq latency
  vf2 E = vfma(vfma((vf2){B4, B4}, s, (vf2){B2, B2}), s, (vf2){1.f, 1.f});
  vf2 O = vfma((vf2){B3, B3}, s, (vf2){B1, B1});
  vf2 dd = s * ri;
  vf2 p = vfma(dd, O, E);
  vf2 y;
  y.x = FRCP(p.x);
  y.y = FRCP(p.y);
  vf2 y2 = y * y;
  vf2 y4 = y2 * y2;
  vf2 w = vfma(-y4, ri, ri);  // erf(d/sqrt2)/d
  acc = vfma(qk, w, acc);
}

template <bool CHECK>
__device__ __forceinline__ vf2 tile_sum(const float4* __restrict__ tile,
                                        int jbeg, int i0, vf2 xi, vf2 yi,
                                        vf2 zi) {
  // preload the ENTIRE 16-entry tile into registers: 16 ds_read_b128 issued
  // back-to-back, ONE latency exposure for the whole loop
  float4 t0 = tile[0], t1 = tile[1], t2 = tile[2], t3 = tile[3];
  float4 t4 = tile[4], t5 = tile[5], t6 = tile[6], t7 = tile[7];
  float4 t8 = tile[8], t9 = tile[9], t10 = tile[10], t11 = tile[11];
  float4 t12 = tile[12], t13 = tile[13], t14 = tile[14], t15 = tile[15];

  // 4 vf2 accumulators = 8 independent scalar chains
  vf2 a0 = {0.f, 0.f}, a1 = {0.f, 0.f}, a2 = {0.f, 0.f}, a3 = {0.f, 0.f};
  pair2_body<CHECK>(t0, jbeg + 0, i0, xi, yi, zi, a0);
  pair2_body<CHECK>(t1, jbeg + 1, i0, xi, yi, zi, a1);
  pair2_body<CHECK>(t2, jbeg + 2, i0, xi, yi, zi, a2);
  pair2_body<CHECK>(t3, jbeg + 3, i0, xi, yi, zi, a3);
  pair2_body<CHECK>(t4, jbeg + 4, i0, xi, yi, zi, a0);
  pair2_body<CHECK>(t5, jbeg + 5, i0, xi, yi, zi, a1);
  pair2_body<CHECK>(t6, jbeg + 6, i0, xi, yi, zi, a2);
  pair2_body<CHECK>(t7, jbeg + 7, i0, xi, yi, zi, a3);
  pair2_body<CHECK>(t8, jbeg + 8, i0, xi, yi, zi, a0);
  pair2_body<CHECK>(t9, jbeg + 9, i0, xi, yi, zi, a1);
  pair2_body<CHECK>(t10, jbeg + 10, i0, xi, yi, zi, a2);
  pair2_body<CHECK>(t11, jbeg + 11, i0, xi, yi, zi, a3);
  pair2_body<CHECK>(t12, jbeg + 12, i0, xi, yi, zi, a0);
  pair2_body<CHECK>(t13, jbeg + 13, i0, xi, yi, zi, a1);
  pair2_body<CHECK>(t14, jbeg + 14, i0, xi, yi, zi, a2);
  pair2_body<CHECK>(t15, jbeg + 15, i0, xi, yi, zi, a3);
  return (a0 + a1) + (a2 + a3);
}

__global__ __launch_bounds__(256) void ewald_tri(
    const float* __restrict__ q, const float* __restrict__ r,
    float* __restrict__ partial, int n) {
  const int tid = threadIdx.x;
  const int bid = blockIdx.x;
  const int lane = tid & 63;
  const int wid = tid >> 6;
  const int jslices = (n + 15) >> 4;  // 16-wide j-slices

  // invert bid -> (ib, js): active js for 512-wide i-block ib: [32*ib, jslices)
  int ib = 0, cum = 0;
  while (true) {
    int c = jslices - 32 * ib;
    if (c <= 0 || cum + c > bid) break;
    cum += c;
    ++ib;
  }
  const int js = 32 * ib + (bid - cum);

  const int ibeg = ib << 9;  // 512-wide i-block
  const int jbeg = js << 4;  // 16-wide j-tile
  const bool pure_above = (jbeg >= ibeg + 512);

  // stage the 16-particle j-tile once (256B)
  __shared__ float4 tile[16];
  if (tid < 16) {
    int j = jbeg + tid;
    float4 v = make_float4(1e10f, 1e10f, 1e10f, 0.f);
    if (j < n) v = make_float4(r[3 * j], r[3 * j + 1], r[3 * j + 2], q[j]);
    tile[tid] = v;
  }

  // wave wid owns i-strip [ibeg+128*wid, +128); lane handles i0 and i0+64
  const int i0 = ibeg + (wid << 7) + lane;
  const int i1 = i0 + 64;
  float qi0 = 0.f, qi1 = 0.f;
  vf2 xi = {1e10f, 1e10f}, yi = {1e10f, 1e10f}, zi = {1e10f, 1e10f};
  if (i0 < n) {
    qi0 = q[i0];
    xi.x = r[3 * i0];
    yi.x = r[3 * i0 + 1];
    zi.x = r[3 * i0 + 2];
  }
  if (i1 < n) {
    qi1 = q[i1];
    xi.y = r[3 * i1];
    yi.y = r[3 * i1 + 1];
    zi.y = r[3 * i1 + 2];
  }
  __syncthreads();

  vf2 s2;
  if (pure_above)
    s2 = tile_sum<false>(tile, jbeg, i0, xi, yi, zi);
  else
    s2 = tile_sum<true>(tile, jbeg, i0, xi, yi, zi);
  float acc = fmaf(qi0, s2.x, qi1 * s2.y);

  // deterministic block reduce: wave shfl, then cross-wave via LDS
  for (int m = 32; m > 0; m >>= 1) acc += __shfl_xor(acc, m, 64);
  __shared__ float wsum[4];
  if (lane == 0) wsum[wid] = acc;
  __syncthreads();
  if (tid == 0)
    partial[bid] = (wsum[0] + wsum[1]) + (wsum[2] + wsum[3]);
}

__global__ __launch_bounds__(1024) void reduce_partials(
    const float* __restrict__ partial, float* __restrict__ out, int np,
    float scale) {
  const int tid = threadIdx.x;
  float acc = 0.f;
  for (int idx = tid; idx < np; idx += 1024) acc += partial[idx];
  for (int m = 32; m > 0; m >>= 1) acc += __shfl_xor(acc, m, 64);
  __shared__ float wsum[16];
  const int lane = tid & 63;
  const int wid = tid >> 6;
  if (lane == 0) wsum[wid] = acc;
  __syncthreads();
  if (tid == 0) {
    float s = 0.f;
    for (int w = 0; w < 16; ++w) s += wsum[w];
    out[0] = s * scale;
  }
}

extern "C" void kernel_launch(void* const* d_in, const int* in_sizes, int n_in,
                              void* d_out, int out_size, void* d_ws,
                              size_t ws_size, hipStream_t stream) {
  const float* q = (const float*)d_in[0];  // [N,1] fp32
  const float* r = (const float*)d_in[1];  // [N,3] fp32
  const int n = in_sizes[0];
  float* out = (float*)d_out;
  float* partial = (float*)d_ws;

  const int iblocks = (n + 511) / 512;
  const int jslices = (n + 15) / 16;
  int nblocks = 0;
  for (int ib = 0; ib < iblocks; ++ib) {
    int c = jslices - 32 * ib;
    if (c > 0) nblocks += c;
  }

  ewald_tri<<<nblocks, 256, 0, stream>>>(q, r, partial, n);

  // 2 (triangle symmetry) * NORM/(2pi)/2 = NORM/(2pi)
  const float scale = (float)(90.0474 / (2.0 * M_PI));
  reduce_partials<<<1, 1024, 0, stream>>>(partial, out, nblocks, scale);
}

// Round 17
// 17.297 us; speedup vs baseline: 1.0145x; 1.0145x over previous
//
#include <hip/hip_runtime.h>
#include <math.h>

// Realspace Ewald: pot = 2 * sum_{i<j} q_i q_j erf(d_ij/sqrt(2))/d_ij * NORM/(4pi)
// N=6144. FINAL (R12 config, measured best 17.02us): erf via A&S 7.1.23
// rational (absmax 0.0), Estrin split, packed fp32 (2 i-particles/lane ->
// v_pk_*), 512i x 16j active-triangle tiles (2496 blocks, ~9.75 waves/SIMD),
// 4 accumulator chains. Two kernels (fused alternatives measured worse:
// memset-in-graph +39us R4, coop grid.sync +60us R8). Structural probes
// R7/R11/R13/R15/R16 all neutral -> short-kernel prologue/launch floor.

#if __has_builtin(__builtin_amdgcn_rsqf)
#define FRSQ(x) __builtin_amdgcn_rsqf(x)
#else
#define FRSQ(x) rsqrtf(x)
#endif
#if __has_builtin(__builtin_amdgcn_rcpf)
#define FRCP(x) __builtin_amdgcn_rcpf(x)
#else
#define FRCP(x) (1.0f / (x))
#endif

typedef float vf2 __attribute__((ext_vector_type(2)));

__device__ __forceinline__ vf2 vfma(vf2 a, vf2 b, vf2 c) {
  return __builtin_elementwise_fma(a, b, c);
}

// A&S 7.1.23 coefficients pre-multiplied by (1/sqrt(2))^k so poly is in d:
#define B1 0.19685360f
#define B2 0.11519450f
#define B3 0.00034366f
#define B4 0.01952700f

template <bool CHECK>
__device__ __forceinline__ void pair2_body(const float4 v, int jj, int i0,
                                           vf2 xi, vf2 yi, vf2 zi, vf2& acc) {
  vf2 dx = xi - v.x, dy = yi - v.y, dz = zi - v.z;
  vf2 s = vfma(dx, dx, vfma(dy, dy, dz * dz));
  vf2 qk = {v.w, v.w};
  if (CHECK) {
    bool t0 = (jj > i0);
    bool t1 = (jj > i0 + 64);
    s.x = t0 ? s.x : 1.0f;
    s.y = t1 ? s.y : 1.0f;
    qk.x = t0 ? qk.x : 0.0f;
    qk.y = t1 ? qk.y : 0.0f;
  }
  vf2 ri;
  ri.x = FRSQ(s.x);
  ri.y = FRSQ(s.y);
  // Estrin: poly = (1 + B2 s + B4 s^2) + d*(B1 + B3 s); E,O overlap rsq latency
  vf2 E = vfma(vfma((vf2){B4, B4}, s, (vf2){B2, B2}), s, (vf2){1.f, 1.f});
  vf2 O = vfma((vf2){B3, B3}, s, (vf2){B1, B1});
  vf2 dd = s * ri;
  vf2 p = vfma(dd, O, E);
  vf2 y;
  y.x = FRCP(p.x);
  y.y = FRCP(p.y);
  vf2 y2 = y * y;
  vf2 y4 = y2 * y2;
  vf2 w = vfma(-y4, ri, ri);  // erf(d/sqrt2)/d
  acc = vfma(qk, w, acc);
}

template <bool CHECK>
__device__ __forceinline__ vf2 tile_sum(const float4* __restrict__ tile,
                                        int jbeg, int i0, vf2 xi, vf2 yi,
                                        vf2 zi) {
  // 4 accumulator chains: (i0,i1) packed x (even k, odd k)
  vf2 a0 = {0.f, 0.f}, a1 = {0.f, 0.f};
#pragma unroll
  for (int k = 0; k < 16; k += 2) {
    pair2_body<CHECK>(tile[k], jbeg + k, i0, xi, yi, zi, a0);
    pair2_body<CHECK>(tile[k + 1], jbeg + k + 1, i0, xi, yi, zi, a1);
  }
  return a0 + a1;
}

__global__ __launch_bounds__(256) void ewald_tri(
    const float* __restrict__ q, const float* __restrict__ r,
    float* __restrict__ partial, int n) {
  const int tid = threadIdx.x;
  const int bid = blockIdx.x;
  const int lane = tid & 63;
  const int wid = tid >> 6;
  const int jslices = (n + 15) >> 4;  // 16-wide j-slices

  // invert bid -> (ib, js): active js for 512-wide i-block ib: [32*ib, jslices)
  int ib = 0, cum = 0;
  while (true) {
    int c = jslices - 32 * ib;
    if (c <= 0 || cum + c > bid) break;
    cum += c;
    ++ib;
  }
  const int js = 32 * ib + (bid - cum);

  const int ibeg = ib << 9;  // 512-wide i-block
  const int jbeg = js << 4;  // 16-wide j-tile
  const bool pure_above = (jbeg >= ibeg + 512);

  // stage the 16-particle j-tile once (256B)
  __shared__ float4 tile[16];
  if (tid < 16) {
    int j = jbeg + tid;
    float4 v = make_float4(1e10f, 1e10f, 1e10f, 0.f);
    if (j < n) v = make_float4(r[3 * j], r[3 * j + 1], r[3 * j + 2], q[j]);
    tile[tid] = v;
  }

  // wave wid owns i-strip [ibeg+128*wid, +128); lane handles i0 and i0+64
  const int i0 = ibeg + (wid << 7) + lane;
  const int i1 = i0 + 64;
  float qi0 = 0.f, qi1 = 0.f;
  vf2 xi = {1e10f, 1e10f}, yi = {1e10f, 1e10f}, zi = {1e10f, 1e10f};
  if (i0 < n) {
    qi0 = q[i0];
    xi.x = r[3 * i0];
    yi.x = r[3 * i0 + 1];
    zi.x = r[3 * i0 + 2];
  }
  if (i1 < n) {
    qi1 = q[i1];
    xi.y = r[3 * i1];
    yi.y = r[3 * i1 + 1];
    zi.y = r[3 * i1 + 2];
  }
  __syncthreads();

  vf2 s2;
  if (pure_above)
    s2 = tile_sum<false>(tile, jbeg, i0, xi, yi, zi);
  else
    s2 = tile_sum<true>(tile, jbeg, i0, xi, yi, zi);
  float acc = fmaf(qi0, s2.x, qi1 * s2.y);

  // deterministic block reduce: wave shfl, then cross-wave via LDS
  for (int m = 32; m > 0; m >>= 1) acc += __shfl_xor(acc, m, 64);
  __shared__ float wsum[4];
  if (lane == 0) wsum[wid] = acc;
  __syncthreads();
  if (tid == 0)
    partial[bid] = (wsum[0] + wsum[1]) + (wsum[2] + wsum[3]);
}

__global__ __launch_bounds__(256) void reduce_partials(
    const float* __restrict__ partial, float* __restrict__ out, int np4,
    int np, float scale) {
  // np4 = np/4 rounded down; partials read as float4 (L2-resident), tail scalar
  const int tid = threadIdx.x;
  const float4* p4 = (const float4*)partial;
  float acc = 0.f;
  for (int idx = tid; idx < np4; idx += 256) {
    float4 v = p4[idx];
    acc += (v.x + v.y) + (v.z + v.w);
  }
  for (int idx = 4 * np4 + tid; idx < np; idx += 256) acc += partial[idx];
  for (int m = 32; m > 0; m >>= 1) acc += __shfl_xor(acc, m, 64);
  __shared__ float wsum[4];
  const int lane = tid & 63;
  const int wid = tid >> 6;
  if (lane == 0) wsum[wid] = acc;
  __syncthreads();
  if (tid == 0) out[0] = ((wsum[0] + wsum[1]) + (wsum[2] + wsum[3])) * scale;
}

extern "C" void kernel_launch(void* const* d_in, const int* in_sizes, int n_in,
                              void* d_out, int out_size, void* d_ws,
                              size_t ws_size, hipStream_t stream) {
  const float* q = (const float*)d_in[0];  // [N,1] fp32
  const float* r = (const float*)d_in[1];  // [N,3] fp32
  const int n = in_sizes[0];
  float* out = (float*)d_out;
  float* partial = (float*)d_ws;

  const int iblocks = (n + 511) / 512;
  const int jslices = (n + 15) / 16;
  int nblocks = 0;
  for (int ib = 0; ib < iblocks; ++ib) {
    int c = jslices - 32 * ib;
    if (c > 0) nblocks += c;
  }

  ewald_tri<<<nblocks, 256, 0, stream>>>(q, r, partial, n);

  // 2 (triangle symmetry) * NORM/(2pi)/2 = NORM/(2pi)
  const float scale = (float)(90.0474 / (2.0 * M_PI));
  reduce_partials<<<1, 256, 0, stream>>>(partial, out, nblocks / 4, nblocks,
                                         scale);
}